// Round 1
// baseline (7229.212 us; speedup 1.0000x reference)
//
#include <hip/hip_runtime.h>

// GCN: 2x GCNConv(sym-norm, self-loops) + mean-pool + 2 MLP heads.
// Strategy R0: atomic scatter-add edge aggregation (correctness-first).

__device__ __forceinline__ float leaky(float x) { return x > 0.f ? x : 0.01f * x; }

// --- degree: deg[dst] += ew  ---------------------------------------------
__global__ void deg_kernel(const int* __restrict__ dst, const float* __restrict__ ew,
                           float* __restrict__ deg, int E) {
    int e = blockIdx.x * blockDim.x + threadIdx.x;
    if (e < E) atomicAdd(&deg[dst[e]], ew[e]);
}

// --- node pass 1: dinv = rsqrt(deg+1); h1 = X@W1; agg1 = h1*dinv^2 -------
__global__ void node1_kernel(const float* __restrict__ X, const float* __restrict__ W1,
                             float* __restrict__ dinv_io, float* __restrict__ h,
                             float* __restrict__ agg, int N) {
    __shared__ float w[48];
    if (threadIdx.x < 48) w[threadIdx.x] = W1[threadIdx.x];
    __syncthreads();
    int i = blockIdx.x * blockDim.x + threadIdx.x;
    if (i >= N) return;
    float di = rsqrtf(dinv_io[i] + 1.0f);   // buffer holds deg on entry
    dinv_io[i] = di;
    float di2 = di * di;
    float x0 = X[3 * i], x1 = X[3 * i + 1], x2 = X[3 * i + 2];
    float hv[16];
#pragma unroll
    for (int f = 0; f < 16; ++f) hv[f] = x0 * w[f] + x1 * w[16 + f] + x2 * w[32 + f];
    float4* hp = (float4*)(h + (size_t)i * 16);
    float4* ap = (float4*)(agg + (size_t)i * 16);
#pragma unroll
    for (int k = 0; k < 4; ++k) {
        float4 v = make_float4(hv[4 * k], hv[4 * k + 1], hv[4 * k + 2], hv[4 * k + 3]);
        hp[k] = v;
        ap[k] = make_float4(v.x * di2, v.y * di2, v.z * di2, v.w * di2);
    }
}

// --- edge aggregation: agg[dst] += h[src] * (dinv[s]*ew*dinv[d]) ---------
__global__ void edge_kernel(const int* __restrict__ src, const int* __restrict__ dst,
                            const float* __restrict__ ew, const float* __restrict__ dinv,
                            const float* __restrict__ h, float* __restrict__ agg, int E) {
    int e = blockIdx.x * blockDim.x + threadIdx.x;
    if (e >= E) return;
    int s = src[e], d = dst[e];
    float nrm = dinv[s] * ew[e] * dinv[d];
    const float4* hp = (const float4*)(h + (size_t)s * 16);
    float* ap = agg + (size_t)d * 16;
#pragma unroll
    for (int k = 0; k < 4; ++k) {
        float4 v = hp[k];
        atomicAdd(ap + 4 * k + 0, v.x * nrm);
        atomicAdd(ap + 4 * k + 1, v.y * nrm);
        atomicAdd(ap + 4 * k + 2, v.z * nrm);
        atomicAdd(ap + 4 * k + 3, v.w * nrm);
    }
}

// --- node pass 2: x1=leaky(agg1+b1); h2=x1@W2 (in place over agg1);
//                  agg2 = h2*dinv^2  --------------------------------------
__global__ void node2_kernel(const float* __restrict__ b1, const float* __restrict__ W2,
                             const float* __restrict__ dinv,
                             float* __restrict__ agg1_h2, float* __restrict__ agg2, int N) {
    __shared__ float w[256];
    __shared__ float bb[16];
    w[threadIdx.x] = W2[threadIdx.x];           // blockDim == 256
    if (threadIdx.x < 16) bb[threadIdx.x] = b1[threadIdx.x];
    __syncthreads();
    int i = blockIdx.x * blockDim.x + threadIdx.x;
    if (i >= N) return;
    float di = dinv[i];
    float di2 = di * di;
    float x[16];
    const float4* ip = (const float4*)(agg1_h2 + (size_t)i * 16);
#pragma unroll
    for (int k = 0; k < 4; ++k) {
        float4 v = ip[k];
        x[4 * k + 0] = v.x; x[4 * k + 1] = v.y; x[4 * k + 2] = v.z; x[4 * k + 3] = v.w;
    }
#pragma unroll
    for (int f = 0; f < 16; ++f) x[f] = leaky(x[f] + bb[f]);
    float hv[16];
#pragma unroll
    for (int f = 0; f < 16; ++f) {
        float a = 0.f;
#pragma unroll
        for (int k = 0; k < 16; ++k) a += x[k] * w[k * 16 + f];
        hv[f] = a;
    }
    float4* hp = (float4*)(agg1_h2 + (size_t)i * 16);
    float4* ap = (float4*)(agg2 + (size_t)i * 16);
#pragma unroll
    for (int k = 0; k < 4; ++k) {
        float4 v = make_float4(hv[4 * k], hv[4 * k + 1], hv[4 * k + 2], hv[4 * k + 3]);
        hp[k] = v;
        ap[k] = make_float4(v.x * di2, v.y * di2, v.z * di2, v.w * di2);
    }
}

// --- tiny MLP head: 16 ->16 ->16 ->2 -------------------------------------
__device__ void head_mlp(const float* pooled,
                         const float* __restrict__ Wa, const float* __restrict__ ba,
                         const float* __restrict__ Wb, const float* __restrict__ bb,
                         const float* __restrict__ Wc, const float* __restrict__ bc,
                         float* o) {
    float t[16], u[16];
#pragma unroll
    for (int f = 0; f < 16; ++f) {
        float a = ba[f];
        for (int k = 0; k < 16; ++k) a += pooled[k] * Wa[k * 16 + f];
        t[f] = leaky(a);
    }
#pragma unroll
    for (int f = 0; f < 16; ++f) {
        float a = bb[f];
        for (int k = 0; k < 16; ++k) a += t[k] * Wb[k * 16 + f];
        u[f] = leaky(a);
    }
    float o0 = bc[0], o1 = bc[1];
    for (int k = 0; k < 16; ++k) { o0 += u[k] * Wc[2 * k]; o1 += u[k] * Wc[2 * k + 1]; }
    o[0] = o0; o[1] = o1;
}

// --- pool (block per graph; Batching sorted -> binary search) + heads ----
__global__ void pool_head_kernel(const float* __restrict__ agg2, const float* __restrict__ b2,
                                 const int* __restrict__ batching, int N,
                                 const float* __restrict__ Wp1, const float* __restrict__ bp1,
                                 const float* __restrict__ Wp2, const float* __restrict__ bp2,
                                 const float* __restrict__ Wp3, const float* __restrict__ bp3,
                                 const float* __restrict__ Wt1, const float* __restrict__ bt1,
                                 const float* __restrict__ Wt2, const float* __restrict__ bt2,
                                 const float* __restrict__ Wt3, const float* __restrict__ bt3,
                                 float* __restrict__ out) {
    int g = blockIdx.x;
    __shared__ int bounds[2];
    if (threadIdx.x < 2) {
        int v = g + (int)threadIdx.x;
        int lo = 0, hi = N;
        while (lo < hi) { int m = (lo + hi) >> 1; if (batching[m] < v) lo = m + 1; else hi = m; }
        bounds[threadIdx.x] = lo;
    }
    __syncthreads();
    int lo = bounds[0], hi = bounds[1];
    int f = threadIdx.x & 15, r = threadIdx.x >> 4;    // 16 rows x 16 features
    float bf = b2[f];
    float acc = 0.f;
    for (int i = lo + r; i < hi; i += 16) acc += leaky(agg2[(size_t)i * 16 + f] + bf);
    __shared__ float red[16][17];
    red[r][f] = acc;
    __syncthreads();
    __shared__ float pooled[16];
    if (r == 0) {
        float s = 0.f;
#pragma unroll
        for (int k = 0; k < 16; ++k) s += red[k][f];
        pooled[f] = s / fmaxf((float)(hi - lo), 1.0f);
    }
    __syncthreads();
    if (threadIdx.x == 0) {
        float o[2];
        head_mlp(pooled, Wp1, bp1, Wp2, bp2, Wp3, bp3, o);
        out[4 * g + 0] = o[0]; out[4 * g + 1] = o[1];
    } else if (threadIdx.x == 1) {
        float o[2];
        head_mlp(pooled, Wt1, bt1, Wt2, bt2, Wt3, bt3, o);
        out[4 * g + 2] = o[0]; out[4 * g + 3] = o[1];
    }
}

extern "C" void kernel_launch(void* const* d_in, const int* in_sizes, int n_in,
                              void* d_out, int out_size, void* d_ws, size_t ws_size,
                              hipStream_t stream) {
    const float* X        = (const float*)d_in[0];
    const int*   ei       = (const int*)d_in[1];
    const float* ew       = (const float*)d_in[2];
    const int*   batching = (const int*)d_in[3];
    const float* W1  = (const float*)d_in[5];  const float* b1  = (const float*)d_in[6];
    const float* W2  = (const float*)d_in[7];  const float* b2  = (const float*)d_in[8];
    const float* Wp1 = (const float*)d_in[9];  const float* bp1 = (const float*)d_in[10];
    const float* Wp2 = (const float*)d_in[11]; const float* bp2 = (const float*)d_in[12];
    const float* Wp3 = (const float*)d_in[13]; const float* bp3 = (const float*)d_in[14];
    const float* Wt1 = (const float*)d_in[15]; const float* bt1 = (const float*)d_in[16];
    const float* Wt2 = (const float*)d_in[17]; const float* bt2 = (const float*)d_in[18];
    const float* Wt3 = (const float*)d_in[19]; const float* bt3 = (const float*)d_in[20];

    const int N = in_sizes[3];        // 262144
    const int E = in_sizes[2];        // 4194304
    const int G = out_size / 4;       // 1024
    const int* src = ei;
    const int* dst = ei + E;

    char* ws = (char*)d_ws;
    float* deg_dinv = (float*)ws;                                 // N floats
    float* h1       = (float*)(ws + (size_t)N * 4);               // N*16
    float* aggA     = h1 + (size_t)N * 16;                        // N*16 (agg1 -> h2)
    float* aggB     = aggA + (size_t)N * 16;                      // N*16 (agg2)
    float* out      = (float*)d_out;

    hipMemsetAsync(deg_dinv, 0, (size_t)N * 4, stream);

    int tb = 256;
    deg_kernel<<<(E + tb - 1) / tb, tb, 0, stream>>>(dst, ew, deg_dinv, E);
    node1_kernel<<<(N + tb - 1) / tb, tb, 0, stream>>>(X, W1, deg_dinv, h1, aggA, N);
    edge_kernel<<<(E + tb - 1) / tb, tb, 0, stream>>>(src, dst, ew, deg_dinv, h1, aggA, E);
    node2_kernel<<<(N + tb - 1) / tb, tb, 0, stream>>>(b1, W2, deg_dinv, aggA, aggB, N);
    edge_kernel<<<(E + tb - 1) / tb, tb, 0, stream>>>(src, dst, ew, deg_dinv, aggA, aggB, E);
    pool_head_kernel<<<G, tb, 0, stream>>>(aggB, b2, batching, N,
                                           Wp1, bp1, Wp2, bp2, Wp3, bp3,
                                           Wt1, bt1, Wt2, bt2, Wt3, bt3, out);
}

// Round 2
// 898.491 us; speedup vs baseline: 8.0459x; 8.0459x over previous
//
#include <hip/hip_runtime.h>

// GCN: 2x GCNConv(sym-norm, self-loops) + mean-pool + 2 MLP heads.
// Strategy R1: build dst-CSR per call (hist -> scan -> scatter), then
// gather-based aggregation (4 lanes/node, float4 per lane, register acc).
// No float atomics in the feature path (R0's 67M atomics/pass = 3.4 ms each).

__device__ __forceinline__ float leaky(float x) { return x > 0.f ? x : 0.01f * x; }

// --- 1. histogram of dst -------------------------------------------------
__global__ void hist_kernel(const int* __restrict__ dst, int* __restrict__ counts, int E) {
    int e = blockIdx.x * blockDim.x + threadIdx.x;
    if (e < E) atomicAdd(&counts[dst[e]], 1);
}

// --- 2. two-level exclusive scan (N = 256 blocks x 1024) -----------------
__global__ void scan1_kernel(const int* __restrict__ counts, int* __restrict__ row,
                             int* __restrict__ bsum) {
    __shared__ int s[1024];
    int t = threadIdx.x;
    int gid = blockIdx.x * 1024 + t;
    int v = counts[gid];
    s[t] = v;
    __syncthreads();
    for (int off = 1; off < 1024; off <<= 1) {
        int x = (t >= off) ? s[t - off] : 0;
        __syncthreads();
        s[t] += x;
        __syncthreads();
    }
    row[gid] = s[t] - v;                 // exclusive within block
    if (t == 1023) bsum[blockIdx.x] = s[t];
}

__global__ void scan2_kernel(int* __restrict__ bsum) {   // 1 block x 256
    __shared__ int s[256];
    int t = threadIdx.x;
    int v = bsum[t];
    s[t] = v;
    __syncthreads();
    for (int off = 1; off < 256; off <<= 1) {
        int x = (t >= off) ? s[t - off] : 0;
        __syncthreads();
        s[t] += x;
        __syncthreads();
    }
    bsum[t] = s[t] - v;                  // exclusive
}

__global__ void scan3_kernel(int* __restrict__ row, int* __restrict__ cursor,
                             const int* __restrict__ bsum, int N, int E) {
    int gid = blockIdx.x * blockDim.x + threadIdx.x;
    if (gid < N) {
        int r = row[gid] + bsum[gid >> 10];
        row[gid] = r;
        cursor[gid] = r;
    }
    if (gid == 0) row[N] = E;
}

// --- 3. scatter edges into CSR slots: edata[p] = (src, ew) ---------------
__global__ void scatter_kernel(const int* __restrict__ src, const int* __restrict__ dst,
                               const float* __restrict__ ew, int* __restrict__ cursor,
                               int2* __restrict__ edata, int E) {
    int e = blockIdx.x * blockDim.x + threadIdx.x;
    if (e >= E) return;
    int d = dst[e];
    int p = atomicAdd(&cursor[d], 1);
    edata[p] = make_int2(src[e], __float_as_int(ew[e]));
}

// --- 4. per-node: deg from CSR row, dinv, h1 = X@W1 ----------------------
__global__ void node1_kernel(const float* __restrict__ X, const float* __restrict__ W1,
                             const int* __restrict__ row, const int2* __restrict__ edata,
                             float* __restrict__ dinv, float* __restrict__ h, int N) {
    __shared__ float w[48];
    if (threadIdx.x < 48) w[threadIdx.x] = W1[threadIdx.x];
    __syncthreads();
    int i = blockIdx.x * blockDim.x + threadIdx.x;
    if (i >= N) return;
    int beg = row[i], end = row[i + 1];
    float deg = 1.0f;                    // self-loop weight
    for (int e = beg; e < end; ++e) deg += __int_as_float(edata[e].y);
    dinv[i] = rsqrtf(deg);
    float x0 = X[3 * i], x1 = X[3 * i + 1], x2 = X[3 * i + 2];
    float4* hp = (float4*)(h + (size_t)i * 16);
#pragma unroll
    for (int k = 0; k < 4; ++k) {
        float4 v;
        v.x = x0 * w[4 * k + 0] + x1 * w[16 + 4 * k + 0] + x2 * w[32 + 4 * k + 0];
        v.y = x0 * w[4 * k + 1] + x1 * w[16 + 4 * k + 1] + x2 * w[32 + 4 * k + 1];
        v.z = x0 * w[4 * k + 2] + x1 * w[16 + 4 * k + 2] + x2 * w[32 + 4 * k + 2];
        v.w = x0 * w[4 * k + 3] + x1 * w[16 + 4 * k + 3] + x2 * w[32 + 4 * k + 3];
        hp[k] = v;
    }
}

// --- 5. gather aggregation: 4 lanes per node, float4 per lane ------------
// agg[i] = sum_e h[src_e]*(dinv[src]*ew*dinv[i]) + h[i]*dinv[i]^2
__global__ void agg_kernel(const int* __restrict__ row, const int2* __restrict__ edata,
                           const float* __restrict__ dinv, const float* __restrict__ h,
                           float* __restrict__ agg, int N) {
    int t = blockIdx.x * blockDim.x + threadIdx.x;
    int i = t >> 2, l = t & 3;
    if (i >= N) return;
    int beg = row[i], end = row[i + 1];
    float di = dinv[i];
    const float4* hp = (const float4*)h;
    float4 self = hp[i * 4 + l];
    float di2 = di * di;
    float4 acc = make_float4(self.x * di2, self.y * di2, self.z * di2, self.w * di2);
    for (int e = beg; e < end; ++e) {
        int2 ed = edata[e];
        int s = ed.x;
        float nrm = dinv[s] * __int_as_float(ed.y) * di;
        float4 v = hp[s * 4 + l];
        acc.x += v.x * nrm; acc.y += v.y * nrm; acc.z += v.z * nrm; acc.w += v.w * nrm;
    }
    ((float4*)agg)[i * 4 + l] = acc;
}

// --- 6. x1 = leaky(aggA+b1); h2 = x1@W2 (in place over aggA ok per-thread,
//         but written to hbuf for pass 2) --------------------------------
__global__ void node2_kernel(const float* __restrict__ b1, const float* __restrict__ W2,
                             const float* __restrict__ aggA, float* __restrict__ h2, int N) {
    __shared__ float w[256];
    __shared__ float bb[16];
    w[threadIdx.x] = W2[threadIdx.x];    // blockDim == 256
    if (threadIdx.x < 16) bb[threadIdx.x] = b1[threadIdx.x];
    __syncthreads();
    int i = blockIdx.x * blockDim.x + threadIdx.x;
    if (i >= N) return;
    float x[16];
    const float4* ip = (const float4*)(aggA + (size_t)i * 16);
#pragma unroll
    for (int k = 0; k < 4; ++k) {
        float4 v = ip[k];
        x[4 * k + 0] = v.x; x[4 * k + 1] = v.y; x[4 * k + 2] = v.z; x[4 * k + 3] = v.w;
    }
#pragma unroll
    for (int f = 0; f < 16; ++f) x[f] = leaky(x[f] + bb[f]);
    float4* hp = (float4*)(h2 + (size_t)i * 16);
#pragma unroll
    for (int k = 0; k < 4; ++k) {
        float4 v;
#pragma unroll
        for (int c = 0; c < 4; ++c) {
            int f = 4 * k + c;
            float a = 0.f;
#pragma unroll
            for (int q = 0; q < 16; ++q) a += x[q] * w[q * 16 + f];
            ((float*)&v)[c] = a;
        }
        hp[k] = v;
    }
}

// --- tiny MLP head: 16 ->16 ->16 ->2 -------------------------------------
__device__ void head_mlp(const float* pooled,
                         const float* __restrict__ Wa, const float* __restrict__ ba,
                         const float* __restrict__ Wb, const float* __restrict__ bb,
                         const float* __restrict__ Wc, const float* __restrict__ bc,
                         float* o) {
    float t[16], u[16];
#pragma unroll
    for (int f = 0; f < 16; ++f) {
        float a = ba[f];
        for (int k = 0; k < 16; ++k) a += pooled[k] * Wa[k * 16 + f];
        t[f] = leaky(a);
    }
#pragma unroll
    for (int f = 0; f < 16; ++f) {
        float a = bb[f];
        for (int k = 0; k < 16; ++k) a += t[k] * Wb[k * 16 + f];
        u[f] = leaky(a);
    }
    float o0 = bc[0], o1 = bc[1];
    for (int k = 0; k < 16; ++k) { o0 += u[k] * Wc[2 * k]; o1 += u[k] * Wc[2 * k + 1]; }
    o[0] = o0; o[1] = o1;
}

// --- 7. pool (block per graph; Batching sorted -> binary search) + heads -
__global__ void pool_head_kernel(const float* __restrict__ agg2, const float* __restrict__ b2,
                                 const int* __restrict__ batching, int N,
                                 const float* __restrict__ Wp1, const float* __restrict__ bp1,
                                 const float* __restrict__ Wp2, const float* __restrict__ bp2,
                                 const float* __restrict__ Wp3, const float* __restrict__ bp3,
                                 const float* __restrict__ Wt1, const float* __restrict__ bt1,
                                 const float* __restrict__ Wt2, const float* __restrict__ bt2,
                                 const float* __restrict__ Wt3, const float* __restrict__ bt3,
                                 float* __restrict__ out) {
    int g = blockIdx.x;
    __shared__ int bounds[2];
    if (threadIdx.x < 2) {
        int v = g + (int)threadIdx.x;
        int lo = 0, hi = N;
        while (lo < hi) { int m = (lo + hi) >> 1; if (batching[m] < v) lo = m + 1; else hi = m; }
        bounds[threadIdx.x] = lo;
    }
    __syncthreads();
    int lo = bounds[0], hi = bounds[1];
    int f = threadIdx.x & 15, r = threadIdx.x >> 4;    // 16 rows x 16 features
    float bf = b2[f];
    float acc = 0.f;
    for (int i = lo + r; i < hi; i += 16) acc += leaky(agg2[(size_t)i * 16 + f] + bf);
    __shared__ float red[16][17];
    red[r][f] = acc;
    __syncthreads();
    __shared__ float pooled[16];
    if (r == 0) {
        float s = 0.f;
#pragma unroll
        for (int k = 0; k < 16; ++k) s += red[k][f];
        pooled[f] = s / fmaxf((float)(hi - lo), 1.0f);
    }
    __syncthreads();
    if (threadIdx.x == 0) {
        float o[2];
        head_mlp(pooled, Wp1, bp1, Wp2, bp2, Wp3, bp3, o);
        out[4 * g + 0] = o[0]; out[4 * g + 1] = o[1];
    } else if (threadIdx.x == 1) {
        float o[2];
        head_mlp(pooled, Wt1, bt1, Wt2, bt2, Wt3, bt3, o);
        out[4 * g + 2] = o[0]; out[4 * g + 3] = o[1];
    }
}

extern "C" void kernel_launch(void* const* d_in, const int* in_sizes, int n_in,
                              void* d_out, int out_size, void* d_ws, size_t ws_size,
                              hipStream_t stream) {
    const float* X        = (const float*)d_in[0];
    const int*   ei       = (const int*)d_in[1];
    const float* ew       = (const float*)d_in[2];
    const int*   batching = (const int*)d_in[3];
    const float* W1  = (const float*)d_in[5];  const float* b1  = (const float*)d_in[6];
    const float* W2  = (const float*)d_in[7];  const float* b2  = (const float*)d_in[8];
    const float* Wp1 = (const float*)d_in[9];  const float* bp1 = (const float*)d_in[10];
    const float* Wp2 = (const float*)d_in[11]; const float* bp2 = (const float*)d_in[12];
    const float* Wp3 = (const float*)d_in[13]; const float* bp3 = (const float*)d_in[14];
    const float* Wt1 = (const float*)d_in[15]; const float* bt1 = (const float*)d_in[16];
    const float* Wt2 = (const float*)d_in[17]; const float* bt2 = (const float*)d_in[18];
    const float* Wt3 = (const float*)d_in[19]; const float* bt3 = (const float*)d_in[20];

    const int N = in_sizes[3];        // 262144 = 256 * 1024
    const int E = in_sizes[2];        // 4194304
    const int G = out_size / 4;       // 1024
    const int* src = ei;
    const int* dst = ei + E;

    char* ws = (char*)d_ws;
    size_t off = 0;
    int2*  edata = (int2*)(ws + off);  off += (size_t)E * 8;          // 32 MB
    float* h     = (float*)(ws + off); off += (size_t)N * 64;         // 16 MB (h1, then agg2)
    float* aggA  = (float*)(ws + off); off += (size_t)N * 64;         // 16 MB (agg1, then h2... see below)
    float* h2    = (float*)(ws + off); off += (size_t)N * 64;         // 16 MB
    int*   counts= (int*)(ws + off);   off += (size_t)N * 4;
    int*   row   = (int*)(ws + off);   off += (size_t)(N + 1) * 4;
    int*   cursor= (int*)(ws + off);   off += (size_t)N * 4;
    int*   bsum  = (int*)(ws + off);   off += 256 * 4;
    float* dinv  = (float*)(ws + off); off += (size_t)N * 4;
    float* out   = (float*)d_out;

    hipMemsetAsync(counts, 0, (size_t)N * 4, stream);

    const int tb = 256;
    hist_kernel<<<(E + tb - 1) / tb, tb, 0, stream>>>(dst, counts, E);
    scan1_kernel<<<N / 1024, 1024, 0, stream>>>(counts, row, bsum);
    scan2_kernel<<<1, 256, 0, stream>>>(bsum);
    scan3_kernel<<<(N + tb - 1) / tb, tb, 0, stream>>>(row, cursor, bsum, N, E);
    scatter_kernel<<<(E + tb - 1) / tb, tb, 0, stream>>>(src, dst, ew, cursor, edata, E);
    node1_kernel<<<(N + tb - 1) / tb, tb, 0, stream>>>(X, W1, row, edata, dinv, h, N);
    agg_kernel<<<(4 * N + tb - 1) / tb, tb, 0, stream>>>(row, edata, dinv, h, aggA, N);
    node2_kernel<<<(N + tb - 1) / tb, tb, 0, stream>>>(b1, W2, aggA, h2, N);
    agg_kernel<<<(4 * N + tb - 1) / tb, tb, 0, stream>>>(row, edata, dinv, h2, h, N);  // agg2 -> h
    pool_head_kernel<<<G, tb, 0, stream>>>(h, b2, batching, N,
                                           Wp1, bp1, Wp2, bp2, Wp3, bp3,
                                           Wt1, bt1, Wt2, bt2, Wt3, bt3, out);
}

// Round 3
// 496.741 us; speedup vs baseline: 14.5533x; 1.8088x over previous
//
#include <hip/hip_runtime.h>

// GCN: 2x GCNConv(sym-norm, self-loops) + mean-pool + 2 MLP heads.
// Strategy R2: two-pass LDS-binned counting sort for the dst-CSR build
// (replaces hist + 3 scans + cursor-scatter: 8M global atomics -> 0.5M,
// random 8B writes -> coalesced runs). Pass B also emits row[] and dinv[].

#define NBUCK 512          // coarse buckets = dst >> 9
#define BCAP  10240        // slack capacity per bucket (mean 8192, sigma ~90)
#define CHUNK 4096         // edges per pass-A block

__device__ __forceinline__ float leaky(float x) { return x > 0.f ? x : 0.01f * x; }

// --- Pass A: bin edges by dst>>9 into slack-capacity coarse buckets ------
__global__ __launch_bounds__(256) void
binA_kernel(const int* __restrict__ src, const int* __restrict__ dst,
            const float* __restrict__ ew, int* __restrict__ bucketCursor,
            int2* __restrict__ coarse, int E) {
    __shared__ int lhist[NBUCK], lbase[NBUCK], lcur[NBUCK], gbase[NBUCK];
    __shared__ int tmp[256];
    __shared__ int2 stag[CHUNK];
    __shared__ unsigned short sbuck[CHUNK];
    int t = threadIdx.x;
    int base = blockIdx.x * CHUNK;
    for (int b = t; b < NBUCK; b += 256) { lhist[b] = 0; lcur[b] = 0; }
    __syncthreads();
    int n = min(CHUNK, E - base);
    int myDst[16], mySrc[16]; float myEw[16];
#pragma unroll
    for (int k = 0; k < 16; ++k) {
        int j = t + k * 256;                       // coalesced
        if (j < n) {
            int d = dst[base + j];
            myDst[k] = d; mySrc[k] = src[base + j]; myEw[k] = ew[base + j];
            atomicAdd(&lhist[d >> 9], 1);
        } else myDst[k] = -1;
    }
    __syncthreads();
    // exclusive scan of lhist (512 entries, 256 threads, pair trick)
    tmp[t] = lhist[2 * t] + lhist[2 * t + 1];
    __syncthreads();
    for (int off = 1; off < 256; off <<= 1) {
        int v = (t >= off) ? tmp[t - off] : 0;
        __syncthreads();
        tmp[t] += v;
        __syncthreads();
    }
    int pb = (t == 0) ? 0 : tmp[t - 1];
    lbase[2 * t] = pb;
    lbase[2 * t + 1] = pb + lhist[2 * t];
    __syncthreads();
    // reserve global space per bucket (one atomic per non-empty bucket)
    for (int b = t; b < NBUCK; b += 256) {
        int c = lhist[b];
        gbase[b] = c ? atomicAdd(&bucketCursor[b], c) : 0;
    }
    // stage into LDS, sorted by bucket; pack (src | ldst<<18, ew)
    for (int k = 0; k < 16; ++k) {
        int d = myDst[k];
        if (d >= 0) {
            int b = d >> 9;
            int p = lbase[b] + atomicAdd(&lcur[b], 1);
            stag[p] = make_int2(mySrc[k] | ((d & 511) << 18), __float_as_int(myEw[k]));
            sbuck[p] = (unsigned short)b;
        }
    }
    __syncthreads();
    // write out: consecutive j -> consecutive addresses within bucket runs
    for (int j = t; j < n; j += 256) {
        int b = sbuck[j];
        coarse[(size_t)b * BCAP + gbase[b] + (j - lbase[b])] = stag[j];
    }
}

// --- scan bucket counts -> bucket bases (1 block x 512) ------------------
__global__ void bscan_kernel(const int* __restrict__ bucketCursor,
                             int* __restrict__ bucketBase, int* __restrict__ row,
                             int N, int E) {
    __shared__ int s[NBUCK];
    int t = threadIdx.x;
    int v = bucketCursor[t];
    s[t] = v;
    __syncthreads();
    for (int off = 1; off < NBUCK; off <<= 1) {
        int x = (t >= off) ? s[t - off] : 0;
        __syncthreads();
        s[t] += x;
        __syncthreads();
    }
    bucketBase[t] = s[t] - v;
    if (t == 0) row[N] = E;
}

// --- Pass B: fine sort within bucket; emit edata, row, dinv --------------
__global__ __launch_bounds__(256) void
binB_kernel(const int* __restrict__ bucketCursor, const int* __restrict__ bucketBase,
            const int2* __restrict__ coarse, int2* __restrict__ edata,
            int* __restrict__ row, float* __restrict__ dinv, int N) {
    __shared__ int lhist[NBUCK], loff[NBUCK], lcur[NBUCK];
    __shared__ float ldeg[NBUCK];
    __shared__ int tmp[256];
    int b = blockIdx.x, t = threadIdx.x;
    for (int i = t; i < NBUCK; i += 256) { lhist[i] = 0; lcur[i] = 0; ldeg[i] = 0.f; }
    __syncthreads();
    int cnt = bucketCursor[b];
    const int2* cb = coarse + (size_t)b * BCAP;
    for (int j = t; j < cnt; j += 256) {
        int2 e = cb[j];
        int ld = (e.x >> 18) & 511;
        atomicAdd(&lhist[ld], 1);
        atomicAdd(&ldeg[ld], __int_as_float(e.y));
    }
    __syncthreads();
    tmp[t] = lhist[2 * t] + lhist[2 * t + 1];
    __syncthreads();
    for (int off = 1; off < 256; off <<= 1) {
        int v = (t >= off) ? tmp[t - off] : 0;
        __syncthreads();
        tmp[t] += v;
        __syncthreads();
    }
    int pb = (t == 0) ? 0 : tmp[t - 1];
    loff[2 * t] = pb;
    loff[2 * t + 1] = pb + lhist[2 * t];
    __syncthreads();
    int gb = bucketBase[b];
    for (int i = t; i < NBUCK; i += 256) {
        int node = b * NBUCK + i;
        row[node] = gb + loff[i];
        dinv[node] = rsqrtf(1.0f + ldeg[i]);     // +1 = self-loop weight
    }
    for (int j = t; j < cnt; j += 256) {
        int2 e = cb[j];
        int ld = (e.x >> 18) & 511;
        int pos = gb + loff[ld] + atomicAdd(&lcur[ld], 1);
        edata[pos] = make_int2(e.x & 0x3FFFF, e.y);
    }
}

// --- node pass 1: h1 = X@W1 ----------------------------------------------
__global__ void node1_kernel(const float* __restrict__ X, const float* __restrict__ W1,
                             float* __restrict__ h, int N) {
    __shared__ float w[48];
    if (threadIdx.x < 48) w[threadIdx.x] = W1[threadIdx.x];
    __syncthreads();
    int i = blockIdx.x * blockDim.x + threadIdx.x;
    if (i >= N) return;
    float x0 = X[3 * i], x1 = X[3 * i + 1], x2 = X[3 * i + 2];
    float4* hp = (float4*)(h + (size_t)i * 16);
#pragma unroll
    for (int k = 0; k < 4; ++k) {
        float4 v;
        v.x = x0 * w[4 * k + 0] + x1 * w[16 + 4 * k + 0] + x2 * w[32 + 4 * k + 0];
        v.y = x0 * w[4 * k + 1] + x1 * w[16 + 4 * k + 1] + x2 * w[32 + 4 * k + 1];
        v.z = x0 * w[4 * k + 2] + x1 * w[16 + 4 * k + 2] + x2 * w[32 + 4 * k + 2];
        v.w = x0 * w[4 * k + 3] + x1 * w[16 + 4 * k + 3] + x2 * w[32 + 4 * k + 3];
        hp[k] = v;
    }
}

// --- gather aggregation: 4 lanes per node, float4 per lane ---------------
__global__ void agg_kernel(const int* __restrict__ row, const int2* __restrict__ edata,
                           const float* __restrict__ dinv, const float* __restrict__ h,
                           float* __restrict__ agg, int N) {
    int t = blockIdx.x * blockDim.x + threadIdx.x;
    int i = t >> 2, l = t & 3;
    if (i >= N) return;
    int beg = row[i], end = row[i + 1];
    float di = dinv[i];
    const float4* hp = (const float4*)h;
    float4 self = hp[i * 4 + l];
    float di2 = di * di;
    float4 acc = make_float4(self.x * di2, self.y * di2, self.z * di2, self.w * di2);
    for (int e = beg; e < end; ++e) {
        int2 ed = edata[e];
        int s = ed.x;
        float nrm = dinv[s] * __int_as_float(ed.y) * di;
        float4 v = hp[s * 4 + l];
        acc.x += v.x * nrm; acc.y += v.y * nrm; acc.z += v.z * nrm; acc.w += v.w * nrm;
    }
    ((float4*)agg)[i * 4 + l] = acc;
}

// --- x1 = leaky(aggA+b1); h2 = x1@W2 -------------------------------------
__global__ void node2_kernel(const float* __restrict__ b1, const float* __restrict__ W2,
                             const float* __restrict__ aggA, float* __restrict__ h2, int N) {
    __shared__ float w[256];
    __shared__ float bb[16];
    w[threadIdx.x] = W2[threadIdx.x];    // blockDim == 256
    if (threadIdx.x < 16) bb[threadIdx.x] = b1[threadIdx.x];
    __syncthreads();
    int i = blockIdx.x * blockDim.x + threadIdx.x;
    if (i >= N) return;
    float x[16];
    const float4* ip = (const float4*)(aggA + (size_t)i * 16);
#pragma unroll
    for (int k = 0; k < 4; ++k) {
        float4 v = ip[k];
        x[4 * k + 0] = v.x; x[4 * k + 1] = v.y; x[4 * k + 2] = v.z; x[4 * k + 3] = v.w;
    }
#pragma unroll
    for (int f = 0; f < 16; ++f) x[f] = leaky(x[f] + bb[f]);
    float4* hp = (float4*)(h2 + (size_t)i * 16);
#pragma unroll
    for (int k = 0; k < 4; ++k) {
        float4 v;
#pragma unroll
        for (int c = 0; c < 4; ++c) {
            int f = 4 * k + c;
            float a = 0.f;
#pragma unroll
            for (int q = 0; q < 16; ++q) a += x[q] * w[q * 16 + f];
            ((float*)&v)[c] = a;
        }
        hp[k] = v;
    }
}

// --- tiny MLP head: 16 ->16 ->16 ->2 -------------------------------------
__device__ void head_mlp(const float* pooled,
                         const float* __restrict__ Wa, const float* __restrict__ ba,
                         const float* __restrict__ Wb, const float* __restrict__ bb,
                         const float* __restrict__ Wc, const float* __restrict__ bc,
                         float* o) {
    float t[16], u[16];
#pragma unroll
    for (int f = 0; f < 16; ++f) {
        float a = ba[f];
        for (int k = 0; k < 16; ++k) a += pooled[k] * Wa[k * 16 + f];
        t[f] = leaky(a);
    }
#pragma unroll
    for (int f = 0; f < 16; ++f) {
        float a = bb[f];
        for (int k = 0; k < 16; ++k) a += t[k] * Wb[k * 16 + f];
        u[f] = leaky(a);
    }
    float o0 = bc[0], o1 = bc[1];
    for (int k = 0; k < 16; ++k) { o0 += u[k] * Wc[2 * k]; o1 += u[k] * Wc[2 * k + 1]; }
    o[0] = o0; o[1] = o1;
}

// --- pool (block per graph; Batching sorted -> binary search) + heads ----
__global__ void pool_head_kernel(const float* __restrict__ agg2, const float* __restrict__ b2,
                                 const int* __restrict__ batching, int N,
                                 const float* __restrict__ Wp1, const float* __restrict__ bp1,
                                 const float* __restrict__ Wp2, const float* __restrict__ bp2,
                                 const float* __restrict__ Wp3, const float* __restrict__ bp3,
                                 const float* __restrict__ Wt1, const float* __restrict__ bt1,
                                 const float* __restrict__ Wt2, const float* __restrict__ bt2,
                                 const float* __restrict__ Wt3, const float* __restrict__ bt3,
                                 float* __restrict__ out) {
    int g = blockIdx.x;
    __shared__ int bounds[2];
    if (threadIdx.x < 2) {
        int v = g + (int)threadIdx.x;
        int lo = 0, hi = N;
        while (lo < hi) { int m = (lo + hi) >> 1; if (batching[m] < v) lo = m + 1; else hi = m; }
        bounds[threadIdx.x] = lo;
    }
    __syncthreads();
    int lo = bounds[0], hi = bounds[1];
    int f = threadIdx.x & 15, r = threadIdx.x >> 4;    // 16 rows x 16 features
    float bf = b2[f];
    float acc = 0.f;
    for (int i = lo + r; i < hi; i += 16) acc += leaky(agg2[(size_t)i * 16 + f] + bf);
    __shared__ float red[16][17];
    red[r][f] = acc;
    __syncthreads();
    __shared__ float pooled[16];
    if (r == 0) {
        float s = 0.f;
#pragma unroll
        for (int k = 0; k < 16; ++k) s += red[k][f];
        pooled[f] = s / fmaxf((float)(hi - lo), 1.0f);
    }
    __syncthreads();
    if (threadIdx.x == 0) {
        float o[2];
        head_mlp(pooled, Wp1, bp1, Wp2, bp2, Wp3, bp3, o);
        out[4 * g + 0] = o[0]; out[4 * g + 1] = o[1];
    } else if (threadIdx.x == 1) {
        float o[2];
        head_mlp(pooled, Wt1, bt1, Wt2, bt2, Wt3, bt3, o);
        out[4 * g + 2] = o[0]; out[4 * g + 3] = o[1];
    }
}

extern "C" void kernel_launch(void* const* d_in, const int* in_sizes, int n_in,
                              void* d_out, int out_size, void* d_ws, size_t ws_size,
                              hipStream_t stream) {
    const float* X        = (const float*)d_in[0];
    const int*   ei       = (const int*)d_in[1];
    const float* ew       = (const float*)d_in[2];
    const int*   batching = (const int*)d_in[3];
    const float* W1  = (const float*)d_in[5];  const float* b1  = (const float*)d_in[6];
    const float* W2  = (const float*)d_in[7];  const float* b2  = (const float*)d_in[8];
    const float* Wp1 = (const float*)d_in[9];  const float* bp1 = (const float*)d_in[10];
    const float* Wp2 = (const float*)d_in[11]; const float* bp2 = (const float*)d_in[12];
    const float* Wp3 = (const float*)d_in[13]; const float* bp3 = (const float*)d_in[14];
    const float* Wt1 = (const float*)d_in[15]; const float* bt1 = (const float*)d_in[16];
    const float* Wt2 = (const float*)d_in[17]; const float* bt2 = (const float*)d_in[18];
    const float* Wt3 = (const float*)d_in[19]; const float* bt3 = (const float*)d_in[20];

    const int N = in_sizes[3];        // 262144 = 512 * 512
    const int E = in_sizes[2];        // 4194304
    const int G = out_size / 4;       // 1024
    const int* src = ei;
    const int* dst = ei + E;

    char* ws = (char*)d_ws;
    size_t off = 0;
    int2*  edata = (int2*)(ws + off);  off += (size_t)E * 8;              // 32 MB fine CSR
    char*  regionA = ws + off;         off += (size_t)N * 64 * 3;         // 48 MB
    // regionA phase 1: coarse buckets (40 MB); phase 2: h | aggA | h2
    int2*  coarse = (int2*)regionA;
    float* h      = (float*)regionA;                   // h1, later agg2
    float* aggA   = (float*)(regionA + (size_t)N * 64);
    float* h2     = (float*)(regionA + (size_t)N * 128);
    int*   bucketCursor = (int*)(ws + off); off += NBUCK * 4;
    int*   bucketBase   = (int*)(ws + off); off += NBUCK * 4;
    int*   row   = (int*)(ws + off);   off += (size_t)(N + 1) * 4;
    float* dinv  = (float*)(ws + off); off += (size_t)N * 4;
    float* out   = (float*)d_out;

    hipMemsetAsync(bucketCursor, 0, NBUCK * 4, stream);

    const int tb = 256;
    binA_kernel<<<(E + CHUNK - 1) / CHUNK, tb, 0, stream>>>(src, dst, ew, bucketCursor, coarse, E);
    bscan_kernel<<<1, NBUCK, 0, stream>>>(bucketCursor, bucketBase, row, N, E);
    binB_kernel<<<NBUCK, tb, 0, stream>>>(bucketCursor, bucketBase, coarse, edata, row, dinv, N);
    node1_kernel<<<(N + tb - 1) / tb, tb, 0, stream>>>(X, W1, h, N);
    agg_kernel<<<(4 * N + tb - 1) / tb, tb, 0, stream>>>(row, edata, dinv, h, aggA, N);
    node2_kernel<<<(N + tb - 1) / tb, tb, 0, stream>>>(b1, W2, aggA, h2, N);
    agg_kernel<<<(4 * N + tb - 1) / tb, tb, 0, stream>>>(row, edata, dinv, h2, h, N);  // agg2 -> h
    pool_head_kernel<<<G, tb, 0, stream>>>(h, b2, batching, N,
                                           Wp1, bp1, Wp2, bp2, Wp3, bp3,
                                           Wt1, bt1, Wt2, bt2, Wt3, bt3, out);
}